// Round 1
// baseline (34132.010 us; speedup 1.0000x reference)
//
#include <hip/hip_runtime.h>

#define BB 32
#define TSRC 12
#define HORZ 12
#define NN 883
#define DD 10
#define HH 64
#define BN (BB*NN)   // 28256

static __device__ __forceinline__ float sigmf(float x) { return 1.f/(1.f + expf(-x)); }

// ---------------- prep: nv1T/nv2T [10][BN], x0 [BN] ----------------
__global__ __launch_bounds__(256) void prep_kernel(
    const float* __restrict__ tidE1, const float* __restrict__ tidE2,
    const float* __restrict__ diwE1, const float* __restrict__ diwE2,
    const float* __restrict__ nodeE,
    const int* __restrict__ tididx, const int* __restrict__ diwidx,
    int t, int tlen,
    const float* __restrict__ xsrc, int xmode,
    float* __restrict__ nv1T, float* __restrict__ nv2T, float* __restrict__ x0)
{
  int i = blockIdx.x*256 + threadIdx.x;
  if (i >= BN) return;
  int b = i / NN, n = i - b*NN;
  int gi = (b*tlen + t)*NN + n;
  int ti = tididx[gi]*DD, di = diwidx[gi]*DD;
  int nE = n*DD;
#pragma unroll
  for (int d = 0; d < DD; ++d) {
    float E = nodeE[nE+d];
    nv1T[d*BN+i] = tanhf(E * (tidE1[ti+d] * diwE1[di+d]));
    nv2T[d*BN+i] = tanhf(E * (tidE2[ti+d] * diwE2[di+d]));
  }
  x0[i] = (xmode == 0) ? xsrc[gi] : xsrc[i];
}

// ------------- fused softmax(relu(nv1 nv2^T)) @ [x0 | xhT] -> axT [65][BN] -------------
__global__ __launch_bounds__(256) void attn_kernel(
    const float* __restrict__ nv1T, const float* __restrict__ nv2T,
    const float* __restrict__ x0, const float* __restrict__ xhT,
    float* __restrict__ axT)
{
  __shared__ float nv1s[DD][64];
  __shared__ float nv2s[DD][64];
  __shared__ float xt[64][68];   // stride 68 -> 16B aligned float4 at c%4==0
  __shared__ float ps[64][68];
  __shared__ float linv[64];
  int b = blockIdx.y;
  int r0 = blockIdx.x * 64;
  int tid = threadIdx.x;
  int rg = tid >> 4, cg = tid & 15;
  int base = b*NN;

  for (int idx = tid; idx < DD*64; idx += 256) {
    int d = idx >> 6, r = idx & 63;
    nv1s[d][r] = (r0 + r < NN) ? nv1T[d*BN + base + r0 + r] : 0.f;
  }

  float acc[4][4] = {};
  float acc5[4] = {};   // column 64 (cg==0 only)
  float accl[4] = {};   // row sums  (cg==0 only)

  for (int m0 = 0; m0 < NN; m0 += 64) {
    int mv = min(64, NN - m0);
    __syncthreads();
    for (int idx = tid; idx < DD*64; idx += 256) {
      int d = idx >> 6, m = idx & 63;
      nv2s[d][m] = (m0 + m < NN) ? nv2T[d*BN + base + m0 + m] : 0.f;
    }
    for (int idx = tid; idx < 65*64; idx += 256) {
      int c = idx >> 6, m = idx & 63;
      float v = 0.f;
      if (m0 + m < NN) v = (c == 0) ? x0[base + m0 + m] : xhT[(c-1)*BN + base + m0 + m];
      xt[m][c] = v;
    }
    __syncthreads();
    float s[4][4] = {};
#pragma unroll
    for (int d = 0; d < DD; ++d) {
      float4 a4 = *(const float4*)&nv1s[d][rg*4];
      float4 c4 = *(const float4*)&nv2s[d][cg*4];
      const float* ap = (const float*)&a4;
      const float* cp = (const float*)&c4;
#pragma unroll
      for (int j = 0; j < 4; ++j)
#pragma unroll
        for (int jj = 0; jj < 4; ++jj)
          s[j][jj] += ap[j]*cp[jj];
    }
#pragma unroll
    for (int jj = 0; jj < 4; ++jj) {
      int m = cg*4 + jj;
      float4 pv;
      float* pp = (float*)&pv;
#pragma unroll
      for (int j = 0; j < 4; ++j)
        pp[j] = (m < mv) ? expf(fmaxf(s[j][jj], 0.f)) : 0.f;
      *(float4*)&ps[m][rg*4] = pv;
    }
    __syncthreads();
#pragma unroll 4
    for (int m = 0; m < mv; ++m) {
      float4 p4 = *(const float4*)&ps[m][rg*4];
      float4 x4 = *(const float4*)&xt[m][cg*4];
      const float* pp = (const float*)&p4;
      const float* xp = (const float*)&x4;
#pragma unroll
      for (int j = 0; j < 4; ++j)
#pragma unroll
        for (int jj = 0; jj < 4; ++jj)
          acc[j][jj] += pp[j]*xp[jj];
      if (cg == 0) {
        float xx = xt[m][64];
#pragma unroll
        for (int j = 0; j < 4; ++j) { acc5[j] += pp[j]*xx; accl[j] += pp[j]; }
      }
    }
  }
  __syncthreads();
  if (cg == 0) {
#pragma unroll
    for (int j = 0; j < 4; ++j) linv[rg*4+j] = 1.f / accl[j];
  }
  __syncthreads();
#pragma unroll
  for (int j = 0; j < 4; ++j) {
    int r = r0 + rg*4 + j;
    if (r < NN) {
      float il = linv[rg*4+j];
#pragma unroll
      for (int jj = 0; jj < 4; ++jj)
        axT[(cg*4+jj)*BN + base + r] = acc[j][jj]*il;
      if (cg == 0) axT[64*BN + base + r] = acc5[j]*il;
    }
  }
}

// ------------- gate: zr=sigmoid(pdg2), cand-zh = z*h, r out. CO=128 -------------
__global__ __launch_bounds__(256) void gate_kernel(
    const float* __restrict__ x0, const float* __restrict__ xhT,
    const float* __restrict__ axT, const float* __restrict__ nv1T,
    const float* __restrict__ W, const float* __restrict__ bias,
    const float* __restrict__ hT,
    float* __restrict__ czT, float* __restrict__ rT)
{
  __shared__ float Ps[32][132];
  __shared__ float Ws[32][132];
  int n0 = blockIdx.x * 128;
  int tid = threadIdx.x;
  int ng = tid >> 4, og = tid & 15;   // 16 node-groups x 8, 16 o-groups x 8
  float acc[8][8] = {};

  for (int d = 0; d < DD; ++d) {
    for (int k0 = 0; k0 < 130; k0 += 32) {
      __syncthreads();
      for (int idx = tid; idx < 32*128; idx += 256) {
        int ki = idx >> 7, n = idx & 127;
        int gn = n0 + n, kk = k0 + ki;
        float g = 0.f;
        if (gn < BN && kk < 130) {
          float xg;
          if (kk == 0) xg = x0[gn];
          else if (kk < 65) xg = xhT[(kk-1)*BN + gn];
          else xg = axT[(kk-65)*BN + gn];
          g = nv1T[d*BN + gn] * xg;
        }
        Ps[ki][n] = g;
      }
      for (int idx = tid; idx < 32*128; idx += 256) {
        int ki = idx >> 7, o = idx & 127;
        int kk = k0 + ki;
        Ws[ki][o] = (kk < 130) ? W[(d*130 + kk)*128 + o] : 0.f;
      }
      __syncthreads();
#pragma unroll 4
      for (int ki = 0; ki < 32; ++ki) {
        float4 pA = *(const float4*)&Ps[ki][ng*8];
        float4 pB = *(const float4*)&Ps[ki][ng*8+4];
        float4 wA = *(const float4*)&Ws[ki][og*8];
        float4 wB = *(const float4*)&Ws[ki][og*8+4];
        float pv[8] = {pA.x,pA.y,pA.z,pA.w,pB.x,pB.y,pB.z,pB.w};
        float wv[8] = {wA.x,wA.y,wA.z,wA.w,wB.x,wB.y,wB.z,wB.w};
#pragma unroll
        for (int r = 0; r < 8; ++r)
#pragma unroll
          for (int c = 0; c < 8; ++c)
            acc[r][c] += pv[r]*wv[c];
      }
    }
  }

  int nb = n0 + ng*8;
  if (nb >= BN) return;
  // bias: acc += sum_d nv1[n,d]*bias[d][o]
#pragma unroll
  for (int r = 0; r < 8; ++r) {
#pragma unroll
    for (int d = 0; d < DD; ++d) {
      float nvv = nv1T[d*BN + nb + r];
#pragma unroll
      for (int c = 0; c < 8; ++c)
        acc[r][c] += nvv * bias[d*128 + og*8 + c];
    }
  }
#pragma unroll
  for (int c = 0; c < 8; ++c) {
    int o = og*8 + c;
    float v[8];
#pragma unroll
    for (int r = 0; r < 8; ++r) v[r] = sigmf(acc[r][c]);
    if (o < HH) {   // z -> cand = z*h
      float4 h0 = *(const float4*)&hT[o*BN+nb];
      float4 h1 = *(const float4*)&hT[o*BN+nb+4];
      float4 s0 = make_float4(v[0]*h0.x, v[1]*h0.y, v[2]*h0.z, v[3]*h0.w);
      float4 s1 = make_float4(v[4]*h1.x, v[5]*h1.y, v[6]*h1.z, v[7]*h1.w);
      *(float4*)&czT[o*BN+nb]   = s0;
      *(float4*)&czT[o*BN+nb+4] = s1;
    } else {        // r
      *(float4*)&rT[(o-HH)*BN+nb]   = make_float4(v[0],v[1],v[2],v[3]);
      *(float4*)&rT[(o-HH)*BN+nb+4] = make_float4(v[4],v[5],v[6],v[7]);
    }
  }
}

// ------------- upd: hc=tanh(pdg2), h = r*h + (1-r)*hc. CO=64, 128 threads -------------
__global__ __launch_bounds__(128) void upd_kernel(
    const float* __restrict__ x0, const float* __restrict__ czT,
    const float* __restrict__ axT, const float* __restrict__ nv1T,
    const float* __restrict__ W, const float* __restrict__ bias,
    const float* __restrict__ rT, float* __restrict__ hT)
{
  __shared__ float Ps[32][132];
  __shared__ float Ws[32][68];
  int n0 = blockIdx.x * 128;
  int tid = threadIdx.x;
  int ng = tid >> 3, og = tid & 7;    // 16 node-groups x 8, 8 o-groups x 8
  float acc[8][8] = {};

  for (int d = 0; d < DD; ++d) {
    for (int k0 = 0; k0 < 130; k0 += 32) {
      __syncthreads();
      for (int idx = tid; idx < 32*128; idx += 128) {
        int ki = idx >> 7, n = idx & 127;
        int gn = n0 + n, kk = k0 + ki;
        float g = 0.f;
        if (gn < BN && kk < 130) {
          float xg;
          if (kk == 0) xg = x0[gn];
          else if (kk < 65) xg = czT[(kk-1)*BN + gn];
          else xg = axT[(kk-65)*BN + gn];
          g = nv1T[d*BN + gn] * xg;
        }
        Ps[ki][n] = g;
      }
      for (int idx = tid; idx < 32*64; idx += 128) {
        int ki = idx >> 6, o = idx & 63;
        int kk = k0 + ki;
        Ws[ki][o] = (kk < 130) ? W[(d*130 + kk)*64 + o] : 0.f;
      }
      __syncthreads();
#pragma unroll 4
      for (int ki = 0; ki < 32; ++ki) {
        float4 pA = *(const float4*)&Ps[ki][ng*8];
        float4 pB = *(const float4*)&Ps[ki][ng*8+4];
        float4 wA = *(const float4*)&Ws[ki][og*8];
        float4 wB = *(const float4*)&Ws[ki][og*8+4];
        float pv[8] = {pA.x,pA.y,pA.z,pA.w,pB.x,pB.y,pB.z,pB.w};
        float wv[8] = {wA.x,wA.y,wA.z,wA.w,wB.x,wB.y,wB.z,wB.w};
#pragma unroll
        for (int r = 0; r < 8; ++r)
#pragma unroll
          for (int c = 0; c < 8; ++c)
            acc[r][c] += pv[r]*wv[c];
      }
    }
  }

  int nb = n0 + ng*8;
  if (nb >= BN) return;
#pragma unroll
  for (int r = 0; r < 8; ++r) {
#pragma unroll
    for (int d = 0; d < DD; ++d) {
      float nvv = nv1T[d*BN + nb + r];
#pragma unroll
      for (int c = 0; c < 8; ++c)
        acc[r][c] += nvv * bias[d*64 + og*8 + c];
    }
  }
#pragma unroll
  for (int c = 0; c < 8; ++c) {
    int o = og*8 + c;
    float hc[8];
#pragma unroll
    for (int r = 0; r < 8; ++r) hc[r] = tanhf(acc[r][c]);
    float4 r0v = *(const float4*)&rT[o*BN+nb];
    float4 r1v = *(const float4*)&rT[o*BN+nb+4];
    float4 h0 = *(const float4*)&hT[o*BN+nb];
    float4 h1 = *(const float4*)&hT[o*BN+nb+4];
    float4 n0v, n1v;
    n0v.x = r0v.x*h0.x + (1.f-r0v.x)*hc[0];
    n0v.y = r0v.y*h0.y + (1.f-r0v.y)*hc[1];
    n0v.z = r0v.z*h0.z + (1.f-r0v.z)*hc[2];
    n0v.w = r0v.w*h0.w + (1.f-r0v.w)*hc[3];
    n1v.x = r1v.x*h1.x + (1.f-r1v.x)*hc[4];
    n1v.y = r1v.y*h1.y + (1.f-r1v.y)*hc[5];
    n1v.z = r1v.z*h1.z + (1.f-r1v.z)*hc[6];
    n1v.w = r1v.w*h1.w + (1.f-r1v.w)*hc[7];
    *(float4*)&hT[o*BN+nb]   = n0v;
    *(float4*)&hT[o*BN+nb+4] = n1v;
  }
}

// ------------- proj: go = h @ pW^T + pb; write output slice -------------
__global__ __launch_bounds__(256) void proj_kernel(
    const float* __restrict__ hT, const float* __restrict__ pW,
    const float* __restrict__ pb,
    float* __restrict__ go, float* __restrict__ dout, int t)
{
  int i = blockIdx.x*256 + threadIdx.x;
  if (i >= BN) return;
  float s = pb[0];
#pragma unroll
  for (int o = 0; o < HH; ++o) s += hT[o*BN+i]*pW[o];
  go[i] = s;
  int b = i / NN, n = i - b*NN;
  dout[(b*HORZ + t)*NN + n] = s;
}

extern "C" void kernel_launch(void* const* d_in, const int* in_sizes, int n_in,
                              void* d_out, int out_size, void* d_ws, size_t ws_size,
                              hipStream_t stream) {
  (void)in_sizes; (void)n_in; (void)out_size; (void)ws_size;
  const float* src_vals = (const float*)d_in[0];
  const float* node_emb = (const float*)d_in[1];
  const float* tid1 = (const float*)d_in[2];
  const float* tid2 = (const float*)d_in[3];
  const float* diw1 = (const float*)d_in[4];
  const float* diw2 = (const float*)d_in[5];
  const float* egW = (const float*)d_in[6];
  const float* egb = (const float*)d_in[7];
  const float* euW = (const float*)d_in[8];
  const float* eub = (const float*)d_in[9];
  const float* dgW = (const float*)d_in[10];
  const float* dgb = (const float*)d_in[11];
  const float* duW = (const float*)d_in[12];
  const float* dub = (const float*)d_in[13];
  const float* pW  = (const float*)d_in[14];
  const float* pb  = (const float*)d_in[15];
  const int* stid = (const int*)d_in[16];
  const int* sdiw = (const int*)d_in[17];
  const int* ttid = (const int*)d_in[18];
  const int* tdiw = (const int*)d_in[19];
  float* out = (float*)d_out;

  float* w = (float*)d_ws;
  float* hT   = w; w += 64*BN;
  float* czT  = w; w += 64*BN;
  float* rT   = w; w += 64*BN;
  float* axT  = w; w += 65*BN;
  float* nv1T = w; w += 10*BN;
  float* nv2T = w; w += 10*BN;
  float* x0   = w; w += BN;
  float* go   = w; w += BN;

  hipMemsetAsync(hT, 0, sizeof(float)*64*BN, stream);

  dim3 agrid(14, BB);
  for (int t = 0; t < TSRC; ++t) {
    prep_kernel<<<111,256,0,stream>>>(tid1,tid2,diw1,diw2,node_emb,stid,sdiw,t,TSRC,src_vals,0,nv1T,nv2T,x0);
    attn_kernel<<<agrid,256,0,stream>>>(nv1T,nv2T,x0,hT,axT);
    gate_kernel<<<221,256,0,stream>>>(x0,hT,axT,nv1T,egW,egb,hT,czT,rT);
    attn_kernel<<<agrid,256,0,stream>>>(nv1T,nv2T,x0,czT,axT);
    upd_kernel<<<221,128,0,stream>>>(x0,czT,axT,nv1T,euW,eub,rT,hT);
  }
  hipMemsetAsync(go, 0, sizeof(float)*BN, stream);
  for (int t = 0; t < HORZ; ++t) {
    prep_kernel<<<111,256,0,stream>>>(tid1,tid2,diw1,diw2,node_emb,ttid,tdiw,t,HORZ,go,1,nv1T,nv2T,x0);
    attn_kernel<<<agrid,256,0,stream>>>(nv1T,nv2T,x0,hT,axT);
    gate_kernel<<<221,256,0,stream>>>(x0,hT,axT,nv1T,dgW,dgb,hT,czT,rT);
    attn_kernel<<<agrid,256,0,stream>>>(nv1T,nv2T,x0,czT,axT);
    upd_kernel<<<221,128,0,stream>>>(x0,czT,axT,nv1T,duW,dub,rT,hT);
    proj_kernel<<<111,256,0,stream>>>(hT,pW,pb,go,out,t);
  }
}